// Round 4
// baseline (195.099 us; speedup 1.0000x reference)
//
#include <hip/hip_runtime.h>

// RoI2Det: softmax -> threshold -> exact-top-prefix (histogram) -> rank-sort ->
// parallel IoU-bitmatrix + O(keep) serial scan -> top-100.
// B=4, N=2000, C=80 (81 logits w/ background).
//
// Exactness: greedy NMS output depends only on the sorted prefix down to the
// 100th survivor. Normal path sorts the exact top-S (S in [400,512]) selected
// by a fine score histogram, builds the exact suppression matrix (same IEEE
// div as reference), and the serial scan is algebraically the reference
// fori_loop. If <100 keeps occur inside the prefix, mode B rebuilds the exact
// top-2000 (= reference candidate set) and redoes NMS — exact by construction.
//
// Workspace: [0..63] int counts[B]; [64..] u64 keys[B][CAP].
// key = (score_bits<<32) | (0xFFFFFFFF - flat_idx): desc sort == lax.top_k order.

typedef unsigned long long u64;
typedef unsigned int u32;

#define B_ 4
#define N_ 2000
#define C_ 80
#define NCLS 81
#define CAP 8192
#define KPRE 2000
#define MAXDET 100
#define TARGET 400      // normal-path prefix floor (100th survivor ~ rank 130)
#define NB 2312         // score buckets: (bits>>14) - HBASE
#define HBASE 0xF500
#define KSHIFT 46       // key>>46 == score_bits>>14 (monotone in score)
#define CAPA 512        // matrix-NMS capacity
#define CAPB 2048       // escalated prefix capacity (>= 2000 + slack)

__device__ __forceinline__ u64 pack_key(float score, unsigned fi) {
  return ((u64)__float_as_uint(score) << 32) | (u64)(0xFFFFFFFFu - fi);
}

// ---------------- candidate generation ----------------
// 256 threads = 4 waves = 4 proposals/block (2000 blocks: good CU spread).
__global__ __launch_bounds__(256) void cand_kernel(
    const float* __restrict__ cls, u64* __restrict__ gkeys, int* __restrict__ gcnt) {
  __shared__ int s_wc[4], s_woff[4], s_base;
  const int tid = threadIdx.x;
  const int w = tid >> 6, lane = tid & 63;
  const int bpi = N_ / 4;  // 500 blocks per image
  const int b = blockIdx.x / bpi;
  const int n = (blockIdx.x % bpi) * 4 + w;
  const float* lg = cls + (size_t)(b * N_ + n) * NCLS;
  float x0 = lg[lane];
  float x1 = (lane < NCLS - 64) ? lg[64 + lane] : -3.0e38f;
  float mx = fmaxf(x0, x1);
#pragma unroll
  for (int o = 32; o > 0; o >>= 1) mx = fmaxf(mx, __shfl_xor(mx, o));
  float e0 = expf(x0 - mx);
  float e1 = (lane < NCLS - 64) ? expf(x1 - mx) : 0.0f;
  float sum = e0 + e1;
#pragma unroll
  for (int o = 32; o > 0; o >>= 1) sum += __shfl_xor(sum, o);
  float sc0 = e0 / sum, sc1 = e1 / sum;
  bool p0 = sc0 > 0.05f;
  bool p1 = (lane < C_ - 64) && (sc1 > 0.05f);  // class 80 = background
  u64 m0 = __ballot(p0), m1 = __ballot(p1);
  int c0 = __popcll(m0);
  if (lane == 0) s_wc[w] = c0 + __popcll(m1);
  __syncthreads();
  if (tid == 0) {
    int acc = 0;
#pragma unroll
    for (int i = 0; i < 4; ++i) { s_woff[i] = acc; acc += s_wc[i]; }
    s_base = atomicAdd(gcnt + b, acc);
  }
  __syncthreads();
  const int base = s_base + s_woff[w];
  const u64 lt = (1ull << lane) - 1;
  u64* gk = gkeys + (size_t)b * CAP;
  if (p0) {
    int slot = base + __popcll(m0 & lt);
    if (slot < CAP) gk[slot] = pack_key(sc0, (unsigned)(n * C_ + lane));
  }
  if (p1) {
    int slot = base + c0 + __popcll(m1 & lt);
    if (slot < CAP) gk[slot] = pack_key(sc1, (unsigned)(n * C_ + 64 + lane));
  }
}

// ---------------- per-image NMS kernel ----------------
// LDS map (60032 B static), by liveness:
//  [0,9248)      histA               (dead after thresholds saved)
//  [9248,18496)  histB               (dead after thresholds saved)
//  [18496,34880) U    u64[2048]      unsorted keys (dead after rank-scatter)
//  [34880,51264) SS   u64[2048]      sorted keys (live to end)
//  [51264,59456) bxA  float4[512]    mode A boxes | keepB int[2048] (mode B)
//  [0,32768)     rb   u64[512*8]     mode A suppression bit-matrix (over dead hist+U)
//  [0,32000)     bxB  float4[2000]   mode B boxes (over dead hist+U)
//  [59456,59968) outl int[128];  [59968,60032) misc int[16]
// misc: 0=T_A 1=T_B 2=S_A 3=S_B 4=cnt 5=next(modeB) 6=nkept

__device__ __forceinline__ float4 decode_one(
    u64 kk, const float* __restrict__ reg, const float* __restrict__ props,
    int b, float h, float w, float offscale) {
  const float MAXR = 4.135166556742356f;  // |log(16/1000)|
  unsigned fi = 0xFFFFFFFFu - (u32)kk;
  int n = (int)(fi / (unsigned)C_);
  int c = (int)(fi - (unsigned)n * (unsigned)C_);
  float4 p = ((const float4*)props)[b * N_ + n];
  const float* dl = reg + ((size_t)(b * N_ + n)) * (C_ * 4) + c * 4;
  float dx = dl[0] * 0.1f;
  float dy = dl[1] * 0.1f;
  float dw = fminf(fmaxf(dl[2] * 0.2f, -MAXR), MAXR);
  float dh = fminf(fmaxf(dl[3] * 0.2f, -MAXR), MAXR);
  float px = (p.x + p.z) * 0.5f, py = (p.y + p.w) * 0.5f;
  float pw = p.z - p.x, ph = p.w - p.y;
  float gx = px + pw * dx, gy = py + ph * dy;
  float gw = pw * expf(dw), gh = ph * expf(dh);
  float off = (float)c * offscale;  // cross-class IoU exactly 0 after offset
  return make_float4(fminf(fmaxf(gx - gw * 0.5f, 0.0f), w) + off,
                     fminf(fmaxf(gy - gh * 0.5f, 0.0f), h) + off,
                     fminf(fmaxf(gx + gw * 0.5f, 0.0f), w) + off,
                     fminf(fmaxf(gy + gh * 0.5f, 0.0f), h) + off);
}

__global__ __launch_bounds__(1024) void nms_kernel(
    const float* __restrict__ reg, const float* __restrict__ props,
    const int* __restrict__ hw, const u64* __restrict__ gkeys,
    const int* __restrict__ gcnt, float* __restrict__ out) {
  __shared__ u64 lds8[7504];  // 60032 B
  char* bp = (char*)lds8;
  u32* hA = (u32*)(bp + 0);
  u32* hB = (u32*)(bp + 9248);
  u64* U = (u64*)(bp + 18496);
  u64* SS = (u64*)(bp + 34880);
  float4* bxA = (float4*)(bp + 51264);
  u64* rb = (u64*)(bp + 0);          // mode A matrix
  float4* bxB = (float4*)(bp + 0);   // mode B boxes
  int* keepB = (int*)(bp + 51264);
  int* outl = (int*)(bp + 59456);
  int* misc = (int*)(bp + 59968);

  const int b = blockIdx.x, tid = threadIdx.x;
  const int wid = tid >> 6, lane = tid & 63;
  const u64* gk = gkeys + (size_t)b * CAP;
  int M = gcnt[b];
  if (M > CAP) M = CAP;
  float h = (float)hw[b * 2 + 0];
  float w = (float)hw[b * 2 + 1];
  float offscale = fmaxf(h, w) + 1.0f;

  if (tid < 16) misc[tid] = 0;
  for (int i = tid; i < NB; i += 1024) hA[i] = 0;
  __syncthreads();

  // Histogram of score buckets.
  for (int t = tid; t < M; t += 1024) {
    int bi = (int)(gk[t] >> KSHIFT) - HBASE;
    bi = min(max(bi, 0), NB - 1);
    atomicAdd(&hA[bi], 1u);
  }
  __syncthreads();

  // Suffix-inclusive scan (12 passes, ping-pong).
  u32 *src = hA, *dst = hB;
  for (int d = 1; d < NB; d <<= 1) {
    for (int i = tid; i < NB; i += 1024) {
      u32 v = src[i];
      if (i + d < NB) v += src[i + d];
      dst[i] = v;
    }
    __syncthreads();
    u32* tmp = src; src = dst; dst = tmp;
  }

  // Thresholds: T_A (cum>=TARGET), T_B (cum>=KPRE). Hist dies after this.
  for (int i = tid; i < NB; i += 1024) {
    u32 v = src[i];
    if (v >= (u32)TARGET) atomicMax(&misc[0], i);
    if (v >= (u32)KPRE) atomicMax(&misc[1], i);
  }
  __syncthreads();
  if (tid == 0) {
    int TB = misc[1];
    int SB = (int)src[TB];
    if (SB > CAPB && TB + 1 < NB) { TB++; SB = (int)src[TB]; misc[1] = TB; }
    misc[2] = (int)src[misc[0]];
    misc[3] = SB;
  }
  __syncthreads();
  int TA = misc[0], SA = misc[2];
  bool modeB = (SA > CAPA);
  int K = 0, nkept = 0;

  if (!modeB) {
    // Compact buckets >= TA into U (unordered; rank-scatter fixes order).
    if (tid == 0) misc[4] = 0;
    __syncthreads();
    for (int t = tid; t < M; t += 1024) {
      u64 key = gk[t];
      int bi = (int)(key >> KSHIFT) - HBASE;
      bi = min(max(bi, 0), NB - 1);
      if (bi >= TA) { int p = atomicAdd(&misc[4], 1); if (p < CAPA) U[p] = key; }
    }
    __syncthreads();
    int S = misc[4]; if (S > CAPA) S = CAPA;
    // Rank-scatter sort (keys distinct -> perfect permutation), 2 keys/read.
    if (tid == 0 && (S & 1)) U[S] = 0ULL;
    __syncthreads();
    if (tid < S) {
      u64 k1 = U[tid];
      int r1 = 0;
      const ulonglong2* U2 = (const ulonglong2*)U;
      int half = (S + 1) >> 1;
      for (int k = 0; k < half; k++) {
        ulonglong2 kk = U2[k];  // uniform addr -> LDS broadcast
        r1 += (kk.x > k1) + (kk.y > k1);
      }
      SS[r1] = k1;  // U/SS disjoint
    }
    __syncthreads();
    K = S;  // S <= 512 < KPRE
    for (int j = tid; j < K; j += 1024)
      bxA[j] = decode_one(SS[j], reg, props, b, h, w, offscale);
    __syncthreads();

    // Suppression bit-matrix: rb[i][w] bit jj set iff j=64w+jj > i and
    // IoU(box_i, box_j) > 0.5 (exact IEEE div, same as reference).
    int nwords = (S + 63) >> 6;
    int ntiles = nwords * (nwords + 1) / 2;  // upper triangle incl diagonal
    for (int t = wid; t < ntiles; t += 16) {
      int ti = 0, rem = t;
      while (rem >= nwords - ti) { rem -= nwords - ti; ti++; }
      int tj = ti + rem;
      int i = (ti << 6) + lane;
      float4 bi4 = bxA[i];  // i < 512 allocated; garbage ok if i >= S (no write)
      float ai = (bi4.z - bi4.x) * (bi4.w - bi4.y);
      u64 bits = 0;
      int jbase = tj << 6;
      int jcount = min(64, S - jbase);
      for (int jj = 0; jj < jcount; jj++) {
        int j = jbase + jj;
        float4 bj = bxA[j];  // uniform addr -> broadcast
        float aj = (bj.z - bj.x) * (bj.w - bj.y);
        float iw = fmaxf(fminf(bi4.z, bj.z) - fmaxf(bi4.x, bj.x), 0.0f);
        float ih = fmaxf(fminf(bi4.w, bj.w) - fmaxf(bi4.y, bj.y), 0.0f);
        float inter = iw * ih;
        float iou = inter / (ai + aj - inter + 1e-6f);
        if (j > i && iou > 0.5f) bits |= (1ull << jj);
      }
      if (i < S) rb[i * 8 + tj] = bits;
    }
    __syncthreads();

    // Serial greedy scan: ~nkept iterations of bit ops (no shfl, no atomics).
    if (tid == 0) {
      int nk = 0;
      if (S > 0) {
        u64 alive[8];
#pragma unroll
        for (int w2 = 0; w2 < 8; w2++) alive[w2] = (w2 < nwords) ? ~0ull : 0ull;
        int remb = S & 63;
        if (remb) alive[nwords - 1] = (1ull << remb) - 1;
        int i = 0;
        for (;;) {
          outl[nk++] = i;
          if (nk >= MAXDET) break;
          int wi = i >> 6;
          alive[wi] &= ~(1ull << (i & 63));
          const u64* row = rb + i * 8;
          int ni = -1;
          for (int w2 = wi; w2 < nwords; w2++) {  // words < wi are already 0
            u64 a2 = alive[w2] & ~row[w2];        // row[w2>=wi] always written
            alive[w2] = a2;
            if (a2 && ni < 0) ni = (w2 << 6) + (int)__builtin_ctzll(a2);
          }
          if (ni < 0) break;
          i = ni;
        }
      }
      misc[6] = nk;
    }
    __syncthreads();
    nkept = misc[6];
    // Escalate iff <100 keeps and prefix didn't cover min(M, KPRE).
    if (nkept < MAXDET && K < M && K < KPRE) modeB = true;
  }

  if (modeB) {  // never taken in practice; exactness guard (R3's proven path)
    __syncthreads();
    int TB = misc[1];
    if (tid == 0) misc[4] = 0;
    __syncthreads();
    for (int t = tid; t < M; t += 1024) {
      u64 key = gk[t];
      int bi = (int)(key >> KSHIFT) - HBASE;
      bi = min(max(bi, 0), NB - 1);
      if (bi >= TB) { int p = atomicAdd(&misc[4], 1); if (p < CAPB) U[p] = key; }
    }
    __syncthreads();
    int S = misc[4]; if (S > CAPB) S = CAPB;
    {
      int j1 = tid, j2 = tid + 1024;
      u64 k1 = (j1 < S) ? U[j1] : 0ULL;
      u64 k2 = (j2 < S) ? U[j2] : 0ULL;
      int r1 = 0, r2 = 0;
      for (int k = 0; k < S; k++) { u64 kk = U[k]; r1 += (kk > k1); r2 += (kk > k2); }
      __syncthreads();
      if (j1 < S) SS[r1] = k1;
      if (j2 < S) SS[r2] = k2;
    }
    __syncthreads();
    K = (S < KPRE) ? S : KPRE;  // exact top-2000 (or all M if fewer)
    for (int j = tid; j < K; j += 1024) {
      bxB[j] = decode_one(SS[j], reg, props, b, h, w, offscale);
      keepB[j] = 1;
    }
    __syncthreads();
    int nk = 0;
    if (K > 0) {
      int i = 0;
      for (;;) {
        if (tid == 0) { outl[nk] = i; misc[5] = K; }
        nk++;
        if (nk >= MAXDET) break;
        __syncthreads();
        float4 tb = bxB[i];
        float ai = (tb.z - tb.x) * (tb.w - tb.y);
        int ln = K;
        for (int jj = i + 1 + tid; jj < K; jj += 1024) {
          if (!keepB[jj]) continue;
          float4 bj = bxB[jj];
          float aj = (bj.z - bj.x) * (bj.w - bj.y);
          float iw = fmaxf(fminf(tb.z, bj.z) - fmaxf(tb.x, bj.x), 0.0f);
          float ih = fmaxf(fminf(tb.w, bj.w) - fmaxf(tb.y, bj.y), 0.0f);
          float inter = iw * ih;
          float iou = inter / (ai + aj - inter + 1e-6f);
          if (iou > 0.5f) keepB[jj] = 0;
          else ln = min(ln, jj);
        }
#pragma unroll
        for (int off = 32; off; off >>= 1) ln = min(ln, __shfl_xor(ln, off));
        if ((tid & 63) == 0 && ln < K) atomicMin(&misc[5], ln);
        __syncthreads();
        int ni = misc[5];
        __syncthreads();
        if (ni >= K) break;
        i = ni;
      }
    }
    if (tid == 0) misc[6] = nk;
    __syncthreads();
    nkept = misc[6];
  }

  // Output: boxes [B,100,4] | scores [B,100] | labels [B,100] (as float).
  float4* bx = modeB ? bxB : bxA;
  float* oBox = out;
  float* oSc = out + B_ * MAXDET * 4;
  float* oLb = out + B_ * MAXDET * 5;
  for (int k2 = tid; k2 < MAXDET; k2 += 1024) {
    float4 bb = make_float4(0.0f, 0.0f, 0.0f, 0.0f);
    float sv = 0.0f, lv = -1.0f;
    if (k2 < nkept) {
      int idx = outl[k2];
      u64 kk = SS[idx];
      sv = __uint_as_float((u32)(kk >> 32));
      unsigned fi = 0xFFFFFFFFu - (u32)kk;
      int c = (int)(fi % (unsigned)C_);
      float off = (float)c * offscale;
      float4 ob = bx[idx];
      bb = make_float4(ob.x - off, ob.y - off, ob.z - off, ob.w - off);
      lv = (float)c;
    }
    oBox[(b * MAXDET + k2) * 4 + 0] = bb.x;
    oBox[(b * MAXDET + k2) * 4 + 1] = bb.y;
    oBox[(b * MAXDET + k2) * 4 + 2] = bb.z;
    oBox[(b * MAXDET + k2) * 4 + 3] = bb.w;
    oSc[b * MAXDET + k2] = sv;
    oLb[b * MAXDET + k2] = lv;
  }
}

extern "C" void kernel_launch(void* const* d_in, const int* in_sizes, int n_in,
                              void* d_out, int out_size, void* d_ws, size_t ws_size,
                              hipStream_t stream) {
  const float* cls = (const float*)d_in[0];    // [B,N,81] f32
  const float* reg = (const float*)d_in[1];    // [B,N,320] f32
  const float* props = (const float*)d_in[2];  // [B,N,4] f32
  const int* hw = (const int*)d_in[3];         // [B,2] i32
  float* out = (float*)d_out;                  // 2400 f32

  int* gcnt = (int*)d_ws;
  u64* gkeys = (u64*)((char*)d_ws + 64);

  hipMemsetAsync(d_ws, 0, 64, stream);  // zero per-image candidate counts

  cand_kernel<<<B_ * N_ / 4, 256, 0, stream>>>(cls, gkeys, gcnt);
  nms_kernel<<<B_, 1024, 0, stream>>>(reg, props, hw, gkeys, gcnt, out);
}

// Round 5
// 120.005 us; speedup vs baseline: 1.6258x; 1.6258x over previous
//
#include <hip/hip_runtime.h>

// RoI2Det: softmax -> threshold -> exact-top-prefix (hier. histogram) ->
// rank-sort -> parallel IoU-bitmatrix + wave-parallel greedy bit-scan -> top-100.
// B=4, N=2000, C=80 (81 logits w/ background).
//
// Exactness: greedy NMS output depends only on the sorted prefix down to the
// 100th survivor. Mode A sorts the exact top-S (S in [TARGET,CAPA]) selected by
// a fine score histogram (bucket = key>>46, monotone in score); included set ==
// exact global top-S since higher bucket => higher key. If <100 keeps occur
// inside the prefix, mode B rebuilds the exact top-2000 (= reference candidate
// set) and redoes NMS — exact by construction.
//
// Workspace: [0..63] int counts[B][4 segments]; [64..] u64 keys[B][4][2048].
// key = (score_bits<<32) | (0xFFFFFFFF - flat_idx): desc order == lax.top_k order.

typedef unsigned long long u64;
typedef unsigned int u32;

#define B_ 4
#define N_ 2000
#define C_ 80
#define NCLS 81
#define SEG 4
#define SEGCAP 2048
#define CAPIMG 8192     // SEG*SEGCAP
#define KPRE 2000
#define MAXDET 100
#define TARGET 400      // mode-A prefix floor (100th survivor ~ rank 130)
#define NB 2312         // score buckets: (bits>>14) - HBASE
#define NBPAD 2368      // 37*64 (padded for group scan)
#define NG 37
#define HBASE 0xF500
#define KSHIFT 46       // key>>46 == score_bits>>14 (monotone in score)
#define CAPA 512        // matrix-NMS capacity
#define CAPB 2048       // escalated prefix capacity

__device__ __forceinline__ u64 pack_key(float score, unsigned fi) {
  return ((u64)__float_as_uint(score) << 32) | (u64)(0xFFFFFFFFu - fi);
}

// ---------------- candidate generation ----------------
// 1024 thr = 16 waves = 16 proposals/block; 125 blocks/image; ONE global
// atomic per block, spread over 4 per-image segment counters (~31 RMWs each).
__global__ __launch_bounds__(1024) void cand_kernel(
    const float* __restrict__ cls, u64* __restrict__ gkeys, int* __restrict__ gcnt) {
  __shared__ int s_wc[16], s_woff[16], s_base;
  const int tid = threadIdx.x;
  const int w = tid >> 6, lane = tid & 63;
  const int bpi = N_ / 16;  // 125 blocks per image
  const int b = blockIdx.x / bpi;
  const int blk = blockIdx.x % bpi;
  const int g = blk & 3;
  const int n = blk * 16 + w;
  const float* lg = cls + (size_t)(b * N_ + n) * NCLS;
  float x0 = lg[lane];
  float x1 = (lane < NCLS - 64) ? lg[64 + lane] : -3.0e38f;
  float mx = fmaxf(x0, x1);
#pragma unroll
  for (int o = 32; o > 0; o >>= 1) mx = fmaxf(mx, __shfl_xor(mx, o));
  float e0 = expf(x0 - mx);
  float e1 = (lane < NCLS - 64) ? expf(x1 - mx) : 0.0f;
  float sum = e0 + e1;
#pragma unroll
  for (int o = 32; o > 0; o >>= 1) sum += __shfl_xor(sum, o);
  float sc0 = e0 / sum, sc1 = e1 / sum;
  bool p0 = sc0 > 0.05f;
  bool p1 = (lane < C_ - 64) && (sc1 > 0.05f);  // class 80 = background
  u64 m0 = __ballot(p0), m1 = __ballot(p1);
  int c0 = __popcll(m0);
  if (lane == 0) s_wc[w] = c0 + __popcll(m1);
  __syncthreads();
  if (tid == 0) {
    int acc = 0;
#pragma unroll
    for (int i = 0; i < 16; ++i) { s_woff[i] = acc; acc += s_wc[i]; }
    s_base = atomicAdd(gcnt + b * SEG + g, acc);
  }
  __syncthreads();
  const int base = s_base + s_woff[w];
  const u64 lt = (1ull << lane) - 1;
  u64* gk = gkeys + (size_t)b * CAPIMG + (size_t)g * SEGCAP;
  if (p0) {
    int slot = base + __popcll(m0 & lt);
    if (slot < SEGCAP) gk[slot] = pack_key(sc0, (unsigned)(n * C_ + lane));
  }
  if (p1) {
    int slot = base + c0 + __popcll(m1 & lt);
    if (slot < SEGCAP) gk[slot] = pack_key(sc1, (unsigned)(n * C_ + 64 + lane));
  }
}

// ---------------- per-image NMS kernel ----------------
// LDS map (60288 B), by liveness:
//  [0,9472)      hist u32[2368]     (mode A; dead after T_A found)
//  [0,32768)     rb   u64[512*8]    mode A bit-matrix (after decode)
//  [0,9248)+[9248,18496) hA/hB      (mode B full scan)
//  [0,32000)     bxB  float4[2000]  (mode B, over dead hA/hB/U)
//  [18496,34880) U    u64[2048]     unsorted keys (dead after rank-scatter)
//  [34880,51264) SS   u64[2048]     sorted keys (live to end)
//  [51264,59456) bxA  float4[512]   | keepB int[2048] (mode B)
//  [59456,59968) outl int[128]; [59968,60032) misc int[16]; [60032,60288) coarse int[64]
// misc: 0=T_A 1=T_B 2=S_A 4=cnt 5=next(modeB) 6=nkept

__device__ __forceinline__ float4 decode_one(
    u64 kk, const float* __restrict__ reg, const float* __restrict__ props,
    int b, float h, float w, float offscale) {
  const float MAXR = 4.135166556742356f;  // |log(16/1000)|
  unsigned fi = 0xFFFFFFFFu - (u32)kk;
  int n = (int)(fi / (unsigned)C_);
  int c = (int)(fi - (unsigned)n * (unsigned)C_);
  float4 p = ((const float4*)props)[b * N_ + n];
  const float* dl = reg + ((size_t)(b * N_ + n)) * (C_ * 4) + c * 4;
  float dx = dl[0] * 0.1f;
  float dy = dl[1] * 0.1f;
  float dw = fminf(fmaxf(dl[2] * 0.2f, -MAXR), MAXR);
  float dh = fminf(fmaxf(dl[3] * 0.2f, -MAXR), MAXR);
  float px = (p.x + p.z) * 0.5f, py = (p.y + p.w) * 0.5f;
  float pw = p.z - p.x, ph = p.w - p.y;
  float gx = px + pw * dx, gy = py + ph * dy;
  float gw = pw * expf(dw), gh = ph * expf(dh);
  float off = (float)c * offscale;  // cross-class IoU exactly 0 after offset
  return make_float4(fminf(fmaxf(gx - gw * 0.5f, 0.0f), w) + off,
                     fminf(fmaxf(gy - gh * 0.5f, 0.0f), h) + off,
                     fminf(fmaxf(gx + gw * 0.5f, 0.0f), w) + off,
                     fminf(fmaxf(gy + gh * 0.5f, 0.0f), h) + off);
}

__global__ __launch_bounds__(1024) void nms_kernel(
    const float* __restrict__ reg, const float* __restrict__ props,
    const int* __restrict__ hw, const u64* __restrict__ gkeys,
    const int* __restrict__ gcnt, float* __restrict__ out) {
  __shared__ u64 lds8[7536];  // 60288 B
  char* bp = (char*)lds8;
  u32* hist = (u32*)(bp + 0);
  u64* rb = (u64*)(bp + 0);
  float4* bxB = (float4*)(bp + 0);
  u64* U = (u64*)(bp + 18496);
  u64* SS = (u64*)(bp + 34880);
  float4* bxA = (float4*)(bp + 51264);
  int* keepB = (int*)(bp + 51264);
  int* outl = (int*)(bp + 59456);
  int* misc = (int*)(bp + 59968);
  int* s_coarse = (int*)(bp + 60032);

  const int b = blockIdx.x, tid = threadIdx.x;
  const int wid = tid >> 6, lane = tid & 63;
  const u64* gk = gkeys + (size_t)b * CAPIMG;

  int Mseg[SEG];
  int M = 0;
#pragma unroll
  for (int s = 0; s < SEG; s++) {
    int m = gcnt[b * SEG + s];
    m = min(m, SEGCAP);
    Mseg[s] = m;
    M += m;
  }
  float h = (float)hw[b * 2 + 0];
  float w = (float)hw[b * 2 + 1];
  float offscale = fmaxf(h, w) + 1.0f;

  if (tid < 16) misc[tid] = 0;
  if (tid < 64) s_coarse[tid] = 0;
  for (int i = tid; i < NBPAD; i += 1024) hist[i] = 0;
  __syncthreads();

  // Histogram of score buckets (per segment).
  for (int s = 0; s < SEG; s++) {
    const u64* gs = gk + (size_t)s * SEGCAP;
    for (int t = tid; t < Mseg[s]; t += 1024) {
      int bi = (int)(gs[t] >> KSHIFT) - HBASE;
      bi = min(max(bi, 0), NB - 1);
      atomicAdd(&hist[bi], 1u);
    }
  }
  __syncthreads();

  // Coarse group sums: NG groups of 64 buckets, wave-reduced.
  for (int g2 = wid; g2 < NG; g2 += 16) {
    int v = (int)hist[(g2 << 6) | lane];
#pragma unroll
    for (int o = 32; o; o >>= 1) v += __shfl_xor(v, o);
    if (lane == 0) s_coarse[g2] = v;
  }
  __syncthreads();

  // T_A selection (wave 0): coarse suffix-scan, then fine scan in one group.
  if (tid < 64) {
    int v = s_coarse[lane];  // lanes >= NG read 0
#pragma unroll
    for (int off = 1; off < 64; off <<= 1) {
      int src = lane + off;
      int o = __shfl(v, src < 64 ? src : 63);
      if (src < 64) v += o;  // lanes >= NG stay 0
    }
    u64 pm = __ballot(v >= TARGET);
    int T_A = 0, S_A;
    if (pm) {
      int gs = 63 - __builtin_clzll(pm);  // last group with cum >= TARGET
      int beyond = __shfl(v, gs + 1);     // gs+1 <= 37 < 64; 0 beyond NG
      int fv = (int)hist[(gs << 6) | lane];
#pragma unroll
      for (int off = 1; off < 64; off <<= 1) {
        int src = lane + off;
        int o = __shfl(fv, src < 64 ? src : 63);
        if (src < 64) fv += o;
      }
      int cum = beyond + fv;
      u64 pm2 = __ballot(cum >= TARGET);  // nonzero: cum[0] == csum[gs] >= TARGET
      int tr = 63 - __builtin_clzll(pm2);
      T_A = (gs << 6) + tr;
      S_A = __shfl(cum, tr);
    } else {
      S_A = __shfl(v, 0);  // total M < TARGET: take everything
    }
    if (lane == 0) { misc[0] = T_A; misc[2] = S_A; misc[4] = 0; }
  }
  __syncthreads();
  int T_A = misc[0], S_A = misc[2];
  bool modeB = (S_A > CAPA);
  int K = 0, nkept = 0;

  if (!modeB) {
    // Ballot-aggregated compaction of buckets >= T_A into U.
    for (int s = 0; s < SEG; s++) {
      const u64* gs = gk + (size_t)s * SEGCAP;
      int Mg = Mseg[s];
      for (int t0 = 0; t0 < Mg; t0 += 1024) {
        int t = t0 + tid;
        bool pred = false;
        u64 key = 0;
        if (t < Mg) {
          key = gs[t];
          int bi = (int)(key >> KSHIFT) - HBASE;
          bi = min(max(bi, 0), NB - 1);
          pred = (bi >= T_A);
        }
        u64 mk = __ballot(pred);
        if (mk) {
          int wbase = 0;
          if (lane == 0) wbase = atomicAdd(&misc[4], __popcll(mk));
          wbase = __shfl(wbase, 0);
          if (pred) {
            int pos = wbase + __popcll(mk & ((1ull << lane) - 1));
            if (pos < CAPA) U[pos] = key;
          }
        }
      }
    }
    __syncthreads();
    int S = misc[4];
    if (S > CAPA) S = CAPA;  // == S_A in practice
    // Rank-scatter sort (distinct keys -> perfect permutation), 2 keys/read.
    if (tid == 0 && (S & 1)) U[S] = 0ULL;
    __syncthreads();
    if (tid < S) {
      u64 k1 = U[tid];
      int r1 = 0;
      const ulonglong2* U2 = (const ulonglong2*)U;
      int half = (S + 1) >> 1;
      for (int k = 0; k < half; k++) {
        ulonglong2 kk = U2[k];  // uniform addr -> LDS broadcast
        r1 += (kk.x > k1) + (kk.y > k1);
      }
      SS[r1] = k1;
    }
    __syncthreads();
    K = S;
    for (int j = tid; j < K; j += 1024)
      bxA[j] = decode_one(SS[j], reg, props, b, h, w, offscale);
    __syncthreads();

    // Suppression bit-matrix (hist dead -> rb): rb[i][w] bit jj set iff
    // j = 64w+jj > i and IoU > 0.5 (exact IEEE div, as reference).
    int nwords = (S + 63) >> 6;
    int ntiles = nwords * (nwords + 1) / 2;
    for (int t = wid; t < ntiles; t += 16) {
      int ti = 0, rem = t;
      while (rem >= nwords - ti) { rem -= nwords - ti; ti++; }
      int tj = ti + rem;
      int i = (ti << 6) + lane;
      float4 bi4 = bxA[i];  // i<512 allocated; garbage ok if i>=S (no write)
      float ai = (bi4.z - bi4.x) * (bi4.w - bi4.y);
      u64 bits = 0;
      int jbase = tj << 6;
      int jcount = min(64, S - jbase);
      for (int jj = 0; jj < jcount; jj++) {
        int j = jbase + jj;
        float4 bj = bxA[j];  // uniform addr -> broadcast
        float aj = (bj.z - bj.x) * (bj.w - bj.y);
        float iw = fmaxf(fminf(bi4.z, bj.z) - fmaxf(bi4.x, bj.x), 0.0f);
        float ih = fmaxf(fminf(bi4.w, bj.w) - fmaxf(bi4.y, bj.y), 0.0f);
        float inter = iw * ih;
        float iou = inter / (ai + aj - inter + 1e-6f);
        if (j > i && iou > 0.5f) bits |= (1ull << jj);
      }
      if (i < S) rb[i * 8 + tj] = bits;
    }
    __syncthreads();

    // Wave-parallel greedy bit-scan (wave 0): lanes 0..7 own alive words.
    if (tid < 64) {
      u64 alive = 0;
      if (lane < nwords) {
        alive = ~0ull;
        int remb = S & 63;
        if (lane == nwords - 1 && remb) alive = (1ull << remb) - 1;
      }
      int nk = 0;
      if (S > 0) {
        int i = 0;
        for (;;) {
          if (lane == 0) outl[nk] = i;
          nk++;
          if (nk >= MAXDET) break;
          if (lane == (i >> 6)) alive &= ~(1ull << (i & 63));
          u64 row = (lane < nwords) ? rb[i * 8 + lane] : 0ull;
          // rows w < i>>6 may be unwritten: alive there is 0 -> harmless.
          u64 a2 = alive & ~row;
          alive = a2;
          u64 mk = __ballot(a2 != 0ull);
          if (!mk) break;
          int w2 = (int)__builtin_ctzll(mk);
          u64 aw = __shfl(a2, w2);
          i = (w2 << 6) + (int)__builtin_ctzll(aw);
        }
      }
      if (lane == 0) misc[6] = nk;
    }
    __syncthreads();
    nkept = misc[6];
    // Escalate iff <100 keeps and prefix didn't cover min(M, KPRE).
    if (nkept < MAXDET && K < M && K < KPRE) modeB = true;
  }

  if (modeB) {  // never taken in practice; exact fallback (R4's proven path)
    __syncthreads();
    u32* hA = (u32*)(bp + 0);
    u32* hB = (u32*)(bp + 9248);
    for (int i = tid; i < NB; i += 1024) hA[i] = 0;
    if (tid == 0) { misc[1] = 0; misc[4] = 0; }
    __syncthreads();
    for (int s = 0; s < SEG; s++) {
      const u64* gs = gk + (size_t)s * SEGCAP;
      for (int t = tid; t < Mseg[s]; t += 1024) {
        int bi = (int)(gs[t] >> KSHIFT) - HBASE;
        bi = min(max(bi, 0), NB - 1);
        atomicAdd(&hA[bi], 1u);
      }
    }
    __syncthreads();
    u32 *src = hA, *dst = hB;
    for (int d = 1; d < NB; d <<= 1) {
      for (int i = tid; i < NB; i += 1024) {
        u32 v = src[i];
        if (i + d < NB) v += src[i + d];
        dst[i] = v;
      }
      __syncthreads();
      u32* tmp = src; src = dst; dst = tmp;
    }
    for (int i = tid; i < NB; i += 1024)
      if (src[i] >= (u32)KPRE) atomicMax(&misc[1], i);
    __syncthreads();
    if (tid == 0) {
      int TB = misc[1];
      int SB = (int)src[TB];
      if (SB > CAPB && TB + 1 < NB) misc[1] = TB + 1;  // fat-bucket guard
    }
    __syncthreads();
    int TB = misc[1];
    for (int s = 0; s < SEG; s++) {
      const u64* gs = gk + (size_t)s * SEGCAP;
      for (int t = tid; t < Mseg[s]; t += 1024) {
        u64 key = gs[t];
        int bi = (int)(key >> KSHIFT) - HBASE;
        bi = min(max(bi, 0), NB - 1);
        if (bi >= TB) { int p = atomicAdd(&misc[4], 1); if (p < CAPB) U[p] = key; }
      }
    }
    __syncthreads();
    int S = misc[4]; if (S > CAPB) S = CAPB;
    {
      int j1 = tid, j2 = tid + 1024;
      u64 k1 = (j1 < S) ? U[j1] : 0ULL;
      u64 k2 = (j2 < S) ? U[j2] : 0ULL;
      int r1 = 0, r2 = 0;
      for (int k = 0; k < S; k++) { u64 kk = U[k]; r1 += (kk > k1); r2 += (kk > k2); }
      __syncthreads();
      if (j1 < S) SS[r1] = k1;
      if (j2 < S) SS[r2] = k2;
    }
    __syncthreads();
    K = (S < KPRE) ? S : KPRE;
    for (int j = tid; j < K; j += 1024) {
      bxB[j] = decode_one(SS[j], reg, props, b, h, w, offscale);
      keepB[j] = 1;
    }
    __syncthreads();
    int nk = 0;
    if (K > 0) {
      int i = 0;
      for (;;) {
        if (tid == 0) { outl[nk] = i; misc[5] = K; }
        nk++;
        if (nk >= MAXDET) break;
        __syncthreads();
        float4 tb = bxB[i];
        float ai = (tb.z - tb.x) * (tb.w - tb.y);
        int ln = K;
        for (int jj = i + 1 + tid; jj < K; jj += 1024) {
          if (!keepB[jj]) continue;
          float4 bj = bxB[jj];
          float aj = (bj.z - bj.x) * (bj.w - bj.y);
          float iw = fmaxf(fminf(tb.z, bj.z) - fmaxf(tb.x, bj.x), 0.0f);
          float ih = fmaxf(fminf(tb.w, bj.w) - fmaxf(tb.y, bj.y), 0.0f);
          float inter = iw * ih;
          float iou = inter / (ai + aj - inter + 1e-6f);
          if (iou > 0.5f) keepB[jj] = 0;
          else ln = min(ln, jj);
        }
#pragma unroll
        for (int off = 32; off; off >>= 1) ln = min(ln, __shfl_xor(ln, off));
        if ((tid & 63) == 0 && ln < K) atomicMin(&misc[5], ln);
        __syncthreads();
        int ni = misc[5];
        __syncthreads();
        if (ni >= K) break;
        i = ni;
      }
    }
    if (tid == 0) misc[6] = nk;
    __syncthreads();
    nkept = misc[6];
  }

  // Output: boxes [B,100,4] | scores [B,100] | labels [B,100] (as float).
  float4* bx = modeB ? bxB : bxA;
  float* oBox = out;
  float* oSc = out + B_ * MAXDET * 4;
  float* oLb = out + B_ * MAXDET * 5;
  for (int k2 = tid; k2 < MAXDET; k2 += 1024) {
    float4 bb = make_float4(0.0f, 0.0f, 0.0f, 0.0f);
    float sv = 0.0f, lv = -1.0f;
    if (k2 < nkept) {
      int idx = outl[k2];
      u64 kk = SS[idx];
      sv = __uint_as_float((u32)(kk >> 32));
      unsigned fi = 0xFFFFFFFFu - (u32)kk;
      int c = (int)(fi % (unsigned)C_);
      float off = (float)c * offscale;
      float4 ob = bx[idx];
      bb = make_float4(ob.x - off, ob.y - off, ob.z - off, ob.w - off);
      lv = (float)c;
    }
    oBox[(b * MAXDET + k2) * 4 + 0] = bb.x;
    oBox[(b * MAXDET + k2) * 4 + 1] = bb.y;
    oBox[(b * MAXDET + k2) * 4 + 2] = bb.z;
    oBox[(b * MAXDET + k2) * 4 + 3] = bb.w;
    oSc[b * MAXDET + k2] = sv;
    oLb[b * MAXDET + k2] = lv;
  }
}

extern "C" void kernel_launch(void* const* d_in, const int* in_sizes, int n_in,
                              void* d_out, int out_size, void* d_ws, size_t ws_size,
                              hipStream_t stream) {
  const float* cls = (const float*)d_in[0];    // [B,N,81] f32
  const float* reg = (const float*)d_in[1];    // [B,N,320] f32
  const float* props = (const float*)d_in[2];  // [B,N,4] f32
  const int* hw = (const int*)d_in[3];         // [B,2] i32
  float* out = (float*)d_out;                  // 2400 f32

  int* gcnt = (int*)d_ws;
  u64* gkeys = (u64*)((char*)d_ws + 64);

  hipMemsetAsync(d_ws, 0, 64, stream);  // zero per-image segment counters

  cand_kernel<<<B_ * (N_ / 16), 1024, 0, stream>>>(cls, gkeys, gcnt);
  nms_kernel<<<B_, 1024, 0, stream>>>(reg, props, hw, gkeys, gcnt, out);
}